// Round 2
// baseline (274.300 us; speedup 1.0000x reference)
//
#include <hip/hip_runtime.h>

// BSplineBasis: x[1048576], knots[64] (clamped cubic, 57 uniform interior
// intervals) -> out[1048576, 60] float32.
//
// Only 4 basis values are nonzero per row (local support): compute them with
// the local de Boor triangle (Piegl-Tiller A2.2), then write the 60-float row.
//
// Reference quirk we must reproduce: xn = (x - min)/(max - min + 1e-8) in
// fp32 loses the 1e-8 (range ~9.7, ulp ~1e-6), so the max element has
// xn == 1.0 exactly. The reference's half-open degree-0 indicator
// (x >= t[j]) & (x < t[j+1]) then yields an ALL-ZERO row for that element.
//
// Workspace layout (floats): [0..255] block mins, [256..511] block maxs,
// [512] xmin, [513] range. Needs 2056 B of d_ws.

#define N_BASIS 60

__device__ __forceinline__ float fast_rcp(float a) {
    return __builtin_amdgcn_rcpf(a);  // ~1 ulp; threshold is 2e-2, fine
}

// ---------------- Kernel 1: per-block partial min/max ----------------
__global__ __launch_bounds__(256) void k_partial_minmax(
    const float* __restrict__ x, float* __restrict__ ws, int n4) {
    const int tid = threadIdx.x;
    int gid = blockIdx.x * 256 + tid;
    const int stride = gridDim.x * 256;
    const float4* __restrict__ x4 = (const float4*)x;

    float mn = 3.4028235e38f, mx = -3.4028235e38f;
    for (int i = gid; i < n4; i += stride) {
        float4 v = x4[i];
        mn = fminf(mn, fminf(fminf(v.x, v.y), fminf(v.z, v.w)));
        mx = fmaxf(mx, fmaxf(fmaxf(v.x, v.y), fmaxf(v.z, v.w)));
    }
#pragma unroll
    for (int off = 32; off > 0; off >>= 1) {
        mn = fminf(mn, __shfl_down(mn, off, 64));
        mx = fmaxf(mx, __shfl_down(mx, off, 64));
    }
    __shared__ float smn[4], smx[4];
    if ((tid & 63) == 0) { smn[tid >> 6] = mn; smx[tid >> 6] = mx; }
    __syncthreads();
    if (tid == 0) {
        mn = fminf(fminf(smn[0], smn[1]), fminf(smn[2], smn[3]));
        mx = fmaxf(fmaxf(smx[0], smx[1]), fmaxf(smx[2], smx[3]));
        ws[blockIdx.x] = mn;
        ws[256 + blockIdx.x] = mx;
    }
}

// ---------------- Kernel 2: final reduce, publish xmin + range ----------------
__global__ __launch_bounds__(256) void k_final_minmax(float* __restrict__ ws) {
    const int tid = threadIdx.x;
    float mn = ws[tid];
    float mx = ws[256 + tid];
#pragma unroll
    for (int off = 32; off > 0; off >>= 1) {
        mn = fminf(mn, __shfl_down(mn, off, 64));
        mx = fmaxf(mx, __shfl_down(mx, off, 64));
    }
    __shared__ float smn[4], smx[4];
    if ((tid & 63) == 0) { smn[tid >> 6] = mn; smx[tid >> 6] = mx; }
    __syncthreads();
    if (tid == 0) {
        mn = fminf(fminf(smn[0], smn[1]), fminf(smn[2], smn[3]));
        mx = fmaxf(fmaxf(smx[0], smx[1]), fmaxf(smx[2], smx[3]));
        ws[512] = mn;
        // fp32 add, same as the fp32 reference: the 1e-8 is rounded away for
        // range ~9.7 -> max element normalizes to exactly 1.0 (see header).
        ws[513] = (mx - mn) + 1e-8f;
    }
}

// ---------------- Kernel 3: main — one thread per row ----------------
__global__ __launch_bounds__(256) void k_bspline(
    const float* __restrict__ x, const float* __restrict__ knots,
    const float* __restrict__ ws, float* __restrict__ out, int nrows) {
    __shared__ float t[64];
    if (threadIdx.x < 64) t[threadIdx.x] = knots[threadIdx.x];
    __syncthreads();

    const int row = blockIdx.x * 256 + threadIdx.x;
    if (row >= nrows) return;

    const float xmin = ws[512];
    const float range = ws[513];
    const float xn = (x[row] - xmin) / range;  // fp32, bitwise-matches ref

    // Reference's half-open indicator: xn >= 1.0 (the max element, since the
    // +1e-8 is lost in fp32) falls in NO interval -> all-zero output row.
    const bool live = (xn < 1.0f) && (xn >= 0.0f);

    // Interval i with t[i] <= xn < t[i+1]; interior intervals are uniform
    // width ~1/57 starting at t[3]=0: guess via floor, adjust by one against
    // the actual knot values (exact comparisons -> matches the indicator).
    int ii = (int)(xn * 57.0f);
    ii = ii < 0 ? 0 : (ii > 56 ? 56 : ii);
    int i = ii + 3;
    if (xn < t[i]) i -= 1;
    else if (xn >= t[i + 1]) i += 1;
    i = i < 3 ? 3 : (i > 59 ? 59 : i);

    // Local de Boor (Piegl-Tiller A2.2): N[j] = B_{i-3+j,3}(xn), j=0..3.
    const float l1 = xn - t[i];
    const float l2 = xn - t[i - 1];
    const float l3 = xn - t[i - 2];
    const float r1 = t[i + 1] - xn;
    const float r2 = t[i + 2] - xn;
    const float r3 = t[i + 3] - xn;

    float N0 = 1.0f, N1, N2, N3, temp, saved;
    // d = 1
    temp = N0 * fast_rcp(r1 + l1);
    N0 = r1 * temp;
    N1 = l1 * temp;
    // d = 2
    temp = N0 * fast_rcp(r1 + l2);
    N0 = r1 * temp;
    saved = l2 * temp;
    temp = N1 * fast_rcp(r2 + l1);
    N1 = saved + r2 * temp;
    N2 = l1 * temp;
    // d = 3
    temp = N0 * fast_rcp(r1 + l3);
    N0 = r1 * temp;
    saved = l3 * temp;
    temp = N1 * fast_rcp(r2 + l2);
    N1 = saved + r2 * temp;
    saved = l2 * temp;
    temp = N2 * fast_rcp(r3 + l1);
    N2 = saved + r3 * temp;
    N3 = l1 * temp;

    const float g = live ? 1.0f : 0.0f;  // zero the boundary row
    N0 *= g; N1 *= g; N2 *= g; N3 *= g;

    // Nonzero columns are [i-3, i]. Build the (at most) two nonzero quads.
    const int base = i - 3;         // 0..56
    const int m = base & 3;         // shift within quad
    const int qa = base >> 2;       // 0..14
    const int qb = qa + 1;          // 15 only when m==0 -> QB all-zero anyway

    float4 QA, QB;
    QA.x = (m == 0) ? N0 : 0.0f;
    QA.y = (m == 0) ? N1 : ((m == 1) ? N0 : 0.0f);
    QA.z = (m == 0) ? N2 : ((m == 1) ? N1 : ((m == 2) ? N0 : 0.0f));
    QA.w = (m == 0) ? N3 : ((m == 1) ? N2 : ((m == 2) ? N1 : N0));
    QB.x = (m == 1) ? N3 : ((m == 2) ? N2 : ((m == 3) ? N1 : 0.0f));
    QB.y = (m == 2) ? N3 : ((m == 3) ? N2 : 0.0f);
    QB.z = (m == 3) ? N3 : 0.0f;
    QB.w = 0.0f;

    float4* __restrict__ orow = (float4*)(out + (size_t)row * N_BASIS);
#pragma unroll
    for (int q = 0; q < 15; ++q) {
        float4 v;
        const bool a = (q == qa), b = (q == qb);
        v.x = a ? QA.x : (b ? QB.x : 0.0f);
        v.y = a ? QA.y : (b ? QB.y : 0.0f);
        v.z = a ? QA.z : (b ? QB.z : 0.0f);
        v.w = a ? QA.w : 0.0f;
        orow[q] = v;
    }
}

extern "C" void kernel_launch(void* const* d_in, const int* in_sizes, int n_in,
                              void* d_out, int out_size, void* d_ws, size_t ws_size,
                              hipStream_t stream) {
    const float* x = (const float*)d_in[0];
    const float* knots = (const float*)d_in[1];
    float* out = (float*)d_out;
    float* ws = (float*)d_ws;
    const int nrows = in_sizes[0];

    k_partial_minmax<<<256, 256, 0, stream>>>(x, ws, nrows / 4);
    k_final_minmax<<<1, 256, 0, stream>>>(ws);
    k_bspline<<<(nrows + 255) / 256, 256, 0, stream>>>(x, knots, ws, out, nrows);
}

// Round 3
// 251.265 us; speedup vs baseline: 1.0917x; 1.0917x over previous
//
#include <hip/hip_runtime.h>

// BSplineBasis: x[1048576], knots[64] (clamped cubic, 57 uniform interior
// intervals) -> out[1048576, 60] float32.
//
// Only 4 basis values are nonzero per row (local support): Phase 1 computes
// them with the local de Boor triangle (Piegl-Tiller A2.2) and parks them in
// LDS; Phase 2 writes the block's 3840 contiguous float4s fully coalesced
// (R2 post-mortem: per-row strided float4 stores cost 64 lines/wave-store
// instead of 16 -> main kernel 115us vs 38us write floor).
//
// Reference quirk we must reproduce: xn = (x - min)/(max - min + 1e-8) in
// fp32 loses the 1e-8 (range ~9.7, ulp ~1e-6), so the max element has
// xn == 1.0 exactly. The reference's half-open degree-0 indicator
// (x >= t[j]) & (x < t[j+1]) then yields an ALL-ZERO row for that element.
//
// Workspace layout (floats): [0..255] block mins, [256..511] block maxs,
// [512] xmin, [513] range. Needs 2056 B of d_ws.

#define N_BASIS 60

__device__ __forceinline__ float fast_rcp(float a) {
    return __builtin_amdgcn_rcpf(a);  // ~1 ulp; threshold is 2e-2, fine
}

// ---------------- Kernel 1: per-block partial min/max ----------------
__global__ __launch_bounds__(256) void k_partial_minmax(
    const float* __restrict__ x, float* __restrict__ ws, int n4) {
    const int tid = threadIdx.x;
    int gid = blockIdx.x * 256 + tid;
    const int stride = gridDim.x * 256;
    const float4* __restrict__ x4 = (const float4*)x;

    float mn = 3.4028235e38f, mx = -3.4028235e38f;
    for (int i = gid; i < n4; i += stride) {
        float4 v = x4[i];
        mn = fminf(mn, fminf(fminf(v.x, v.y), fminf(v.z, v.w)));
        mx = fmaxf(mx, fmaxf(fmaxf(v.x, v.y), fmaxf(v.z, v.w)));
    }
#pragma unroll
    for (int off = 32; off > 0; off >>= 1) {
        mn = fminf(mn, __shfl_down(mn, off, 64));
        mx = fmaxf(mx, __shfl_down(mx, off, 64));
    }
    __shared__ float smn[4], smx[4];
    if ((tid & 63) == 0) { smn[tid >> 6] = mn; smx[tid >> 6] = mx; }
    __syncthreads();
    if (tid == 0) {
        mn = fminf(fminf(smn[0], smn[1]), fminf(smn[2], smn[3]));
        mx = fmaxf(fmaxf(smx[0], smx[1]), fmaxf(smx[2], smx[3]));
        ws[blockIdx.x] = mn;
        ws[256 + blockIdx.x] = mx;
    }
}

// ---------------- Kernel 2: final reduce, publish xmin + range ----------------
__global__ __launch_bounds__(256) void k_final_minmax(float* __restrict__ ws) {
    const int tid = threadIdx.x;
    float mn = ws[tid];
    float mx = ws[256 + tid];
#pragma unroll
    for (int off = 32; off > 0; off >>= 1) {
        mn = fminf(mn, __shfl_down(mn, off, 64));
        mx = fmaxf(mx, __shfl_down(mx, off, 64));
    }
    __shared__ float smn[4], smx[4];
    if ((tid & 63) == 0) { smn[tid >> 6] = mn; smx[tid >> 6] = mx; }
    __syncthreads();
    if (tid == 0) {
        mn = fminf(fminf(smn[0], smn[1]), fminf(smn[2], smn[3]));
        mx = fmaxf(fmaxf(smx[0], smx[1]), fmaxf(smx[2], smx[3]));
        ws[512] = mn;
        // fp32 add, same as the fp32 reference: the 1e-8 is rounded away for
        // range ~9.7 -> max element normalizes to exactly 1.0 (see header).
        ws[513] = (mx - mn) + 1e-8f;
    }
}

// ---------------- Kernel 3: main — 256 rows/block, coalesced write-out ------
// Grid must be exactly nrows/256 blocks (nrows = 1048576 = 4096 * 256).
__global__ __launch_bounds__(256) void k_bspline(
    const float* __restrict__ x, const float* __restrict__ knots,
    const float* __restrict__ ws, float* __restrict__ out) {
    __shared__ float t[64];
    __shared__ float4 sN[256];   // the 4 nonzero basis values per row
    __shared__ int sBase[256];   // first nonzero column per row

    const int tid = threadIdx.x;
    if (tid < 64) t[tid] = knots[tid];
    __syncthreads();

    // ---- Phase 1: one thread = one row; local de Boor ----
    const int row = blockIdx.x * 256 + tid;
    const float xmin = ws[512];
    const float range = ws[513];
    const float xn = (x[row] - xmin) / range;  // fp32, bitwise-matches ref

    // Half-open indicator: xn >= 1.0 (the max element) -> all-zero row.
    const bool live = (xn < 1.0f) && (xn >= 0.0f);

    // Interval i with t[i] <= xn < t[i+1]; interior intervals are uniform
    // width ~1/57 starting at t[3]=0: guess via floor, adjust by one against
    // the actual knot values.
    int ii = (int)(xn * 57.0f);
    ii = ii < 0 ? 0 : (ii > 56 ? 56 : ii);
    int i = ii + 3;
    if (xn < t[i]) i -= 1;
    else if (xn >= t[i + 1]) i += 1;
    i = i < 3 ? 3 : (i > 59 ? 59 : i);

    // Local de Boor (Piegl-Tiller A2.2): N[j] = B_{i-3+j,3}(xn), j=0..3.
    const float l1 = xn - t[i];
    const float l2 = xn - t[i - 1];
    const float l3 = xn - t[i - 2];
    const float r1 = t[i + 1] - xn;
    const float r2 = t[i + 2] - xn;
    const float r3 = t[i + 3] - xn;

    float N0 = 1.0f, N1, N2, N3, temp, saved;
    // d = 1
    temp = N0 * fast_rcp(r1 + l1);
    N0 = r1 * temp;
    N1 = l1 * temp;
    // d = 2
    temp = N0 * fast_rcp(r1 + l2);
    N0 = r1 * temp;
    saved = l2 * temp;
    temp = N1 * fast_rcp(r2 + l1);
    N1 = saved + r2 * temp;
    N2 = l1 * temp;
    // d = 3
    temp = N0 * fast_rcp(r1 + l3);
    N0 = r1 * temp;
    saved = l3 * temp;
    temp = N1 * fast_rcp(r2 + l2);
    N1 = saved + r2 * temp;
    saved = l2 * temp;
    temp = N2 * fast_rcp(r3 + l1);
    N2 = saved + r3 * temp;
    N3 = l1 * temp;

    const float g = live ? 1.0f : 0.0f;  // zero the boundary row
    float4 Nv;
    Nv.x = N0 * g; Nv.y = N1 * g; Nv.z = N2 * g; Nv.w = N3 * g;
    sN[tid] = Nv;
    sBase[tid] = i - 3;  // 0..56
    __syncthreads();

    // ---- Phase 2: cooperative, fully-coalesced write-out ----
    // Block's output span: 256 rows * 15 float4 = 3840 contiguous float4s.
    // Thread tid writes p = tid + it*256 -> consecutive lanes, consecutive
    // float4s: 1 KB per wave-store, 16 cache lines (vs 64 strided).
    float4* __restrict__ o4 = (float4*)out + (size_t)blockIdx.x * 3840;
#pragma unroll
    for (int it = 0; it < 15; ++it) {
        const int p = tid + it * 256;
        const unsigned r = (unsigned)p / 15u;   // row within block (magic mul)
        const int j = p - (int)r * 15;          // quad within row, 0..14
        const float4 N = sN[r];                 // <=5 distinct rows per wave
        const int b = sBase[r];
        const int d0 = (j << 2) - b;            // column offset - base
        float4 v;
        v.x = (d0 == 0) ? N.x : (d0 == 1) ? N.y : (d0 == 2) ? N.z : (d0 == 3) ? N.w : 0.0f;
        const int d1 = d0 + 1;
        v.y = (d1 == 0) ? N.x : (d1 == 1) ? N.y : (d1 == 2) ? N.z : (d1 == 3) ? N.w : 0.0f;
        const int d2 = d0 + 2;
        v.z = (d2 == 0) ? N.x : (d2 == 1) ? N.y : (d2 == 2) ? N.z : (d2 == 3) ? N.w : 0.0f;
        const int d3 = d0 + 3;
        v.w = (d3 == 0) ? N.x : (d3 == 1) ? N.y : (d3 == 2) ? N.z : (d3 == 3) ? N.w : 0.0f;
        o4[p] = v;
    }
}

extern "C" void kernel_launch(void* const* d_in, const int* in_sizes, int n_in,
                              void* d_out, int out_size, void* d_ws, size_t ws_size,
                              hipStream_t stream) {
    const float* x = (const float*)d_in[0];
    const float* knots = (const float*)d_in[1];
    float* out = (float*)d_out;
    float* ws = (float*)d_ws;
    const int nrows = in_sizes[0];

    k_partial_minmax<<<256, 256, 0, stream>>>(x, ws, nrows / 4);
    k_final_minmax<<<1, 256, 0, stream>>>(ws);
    k_bspline<<<nrows / 256, 256, 0, stream>>>(x, knots, ws, out);
}